// Round 1
// baseline (1014.927 us; speedup 1.0000x reference)
//
#include <hip/hip_runtime.h>
#include <math.h>

#define N_PTS 65536
#define DIM   64
#define K_CL  128
#define EPSV  1e-8f
#define CAP   8192

// ---------------- ws layout (bytes) ----------------
// 0                : fill_acc[128] float (atomics; zeroed each launch)
// 512              : loss_acc[1]   float (zeroed each launch)
// 1024             : pred_x[N]     int
// 263168           : idx_x[128*CAP] int
// 263168+4194304   : idx_t[128*CAP] int
// 263168+8388608   : count_x[128] int
// 263168+8388608+512 : count_t[128] int
// total ~8.66 MB

__global__ __launch_bounds__(256) void k_zero(float* ws_f) {
  ws_f[threadIdx.x] = 0.0f;  // zeros first 1024 B: fill_acc + loss_acc
}

// one thread per point; centers staged row-major in LDS (broadcast b128 reads)
__global__ __launch_bounds__(256) void k_pred_fill(
    const float* __restrict__ x, const float* __restrict__ centers,
    float* __restrict__ fill_acc, int* __restrict__ pred_x)
{
  __shared__ float c_lds[K_CL * DIM];   // 32 KB
  __shared__ float csq[K_CL];
  __shared__ float fill_lds[K_CL];
  const int tid = threadIdx.x;

  for (int e = tid; e < K_CL * DIM; e += 256) c_lds[e] = centers[e];
  if (tid < K_CL) fill_lds[tid] = 0.0f;
  __syncthreads();
  if (tid < K_CL) {
    float s = 0.0f;
    #pragma unroll 8
    for (int d = 0; d < DIM; ++d) { float v = c_lds[tid * DIM + d]; s += v * v; }
    csq[tid] = s;
  }

  const int i = blockIdx.x * 256 + tid;
  float xr[DIM];
  const float4* xp = reinterpret_cast<const float4*>(x + (size_t)i * DIM);
  #pragma unroll
  for (int q = 0; q < DIM / 4; ++q) {
    float4 v = xp[q];
    xr[4 * q + 0] = v.x; xr[4 * q + 1] = v.y;
    xr[4 * q + 2] = v.z; xr[4 * q + 3] = v.w;
  }
  float xsq = 0.0f;
  #pragma unroll
  for (int d = 0; d < DIM; ++d) xsq += xr[d] * xr[d];
  __syncthreads();

  // ---- pass 1: sumw + argmin (first-index tie-break via strict <) ----
  float sumw = 0.0f;
  float best = INFINITY;
  int   bestj = 0;
  #pragma unroll 4
  for (int j = 0; j < K_CL; ++j) {
    const float* cp = &c_lds[j * DIM];
    float d0 = 0.f, d1 = 0.f, d2a = 0.f, d3 = 0.f;
    #pragma unroll
    for (int d = 0; d < DIM; d += 4) {
      d0  += xr[d + 0] * cp[d + 0];
      d1  += xr[d + 1] * cp[d + 1];
      d2a += xr[d + 2] * cp[d + 2];
      d3  += xr[d + 3] * cp[d + 3];
    }
    float dot  = (d0 + d1) + (d2a + d3);
    float dsq  = xsq + csq[j] - 2.0f * dot;
    float dist = sqrtf(fmaxf(dsq, 0.0f));
    float w    = 1.0f / (dist + EPSV);
    sumw += w;
    if (dist < best) { best = dist; bestj = j; }
  }
  pred_x[i] = bestj;
  const float inv = 1.0f / sumw;
  const int lane = tid & 63;

  // ---- pass 2: normalized weights -> per-cluster sums ----
  #pragma unroll 4
  for (int j = 0; j < K_CL; ++j) {
    const float* cp = &c_lds[j * DIM];
    float d0 = 0.f, d1 = 0.f, d2a = 0.f, d3 = 0.f;
    #pragma unroll
    for (int d = 0; d < DIM; d += 4) {
      d0  += xr[d + 0] * cp[d + 0];
      d1  += xr[d + 1] * cp[d + 1];
      d2a += xr[d + 2] * cp[d + 2];
      d3  += xr[d + 3] * cp[d + 3];
    }
    float dot  = (d0 + d1) + (d2a + d3);
    float dsq  = xsq + csq[j] - 2.0f * dot;
    float dist = sqrtf(fmaxf(dsq, 0.0f));
    float wn   = (1.0f / (dist + EPSV)) * inv;
    #pragma unroll
    for (int off = 32; off > 0; off >>= 1) wn += __shfl_down(wn, off);
    if (lane == 0) atomicAdd(&fill_lds[j], wn);
  }
  __syncthreads();
  if (tid < K_CL) atomicAdd(&fill_acc[tid], fill_lds[tid]);
}

// stable (index-ordered) member-list build: one block per (cluster, side)
__global__ __launch_bounds__(1024) void k_scatter(
    const int* __restrict__ pred_x, const int* __restrict__ pred_t,
    int* __restrict__ idx_x, int* __restrict__ idx_t,
    int* __restrict__ count_x, int* __restrict__ count_t)
{
  const int c    = blockIdx.x >> 1;
  const int side = blockIdx.x & 1;
  const int* __restrict__ pred = side ? pred_t : pred_x;
  int* __restrict__ out = side ? idx_t : idx_x;
  int* __restrict__ cnt = side ? count_t : count_x;

  __shared__ int wsum[16];
  const int tid = threadIdx.x, lane = tid & 63, w = tid >> 6;
  int base = 0;
  for (int start = 0; start < N_PTS; start += 1024) {
    const int i = start + tid;                 // N % 1024 == 0
    const bool m = (pred[i] == c);
    unsigned long long bal = __ballot(m);
    int lp = __popcll(bal & ((1ull << lane) - 1ull));
    if (lane == 0) wsum[w] = __popcll(bal);
    __syncthreads();
    int wbase = 0, tot = 0;
    #pragma unroll
    for (int k = 0; k < 16; ++k) { int v = wsum[k]; tot += v; if (k < w) wbase += v; }
    if (m) { int pos = base + wbase + lp; if (pos < CAP) out[c * CAP + pos] = i; }
    base += tot;
    __syncthreads();
  }
  if (tid == 0) cnt[c] = base;
}

// one block per (cluster, feature): gather, bitonic sort both columns, sum |diff|
__global__ __launch_bounds__(256) void k_w1(
    const float* __restrict__ x, const float* __restrict__ t,
    const int* __restrict__ idx_x, const int* __restrict__ idx_t,
    const int* __restrict__ count_x, const int* __restrict__ count_t,
    float* __restrict__ loss_acc)
{
  __shared__ float sa[CAP];   // 32 KB
  __shared__ float sb[CAP];   // 32 KB  (total exactly 64 KB)
  const int c = blockIdx.x >> 6;
  const int d = blockIdx.x & 63;
  const int cx = min(count_x[c], CAP);
  const int ct = min(count_t[c], CAP);
  const int m  = min(cx, ct);
  if (m == 0) return;

  int P = 1;
  while (P < m) P <<= 1;
  const int tid = threadIdx.x;

  for (int r = tid; r < P; r += 256) {
    sa[r] = (r < m) ? x[(size_t)idx_x[c * CAP + r] * DIM + d] : INFINITY;
    sb[r] = (r < m) ? t[(size_t)idx_t[c * CAP + r] * DIM + d] : INFINITY;
  }
  __syncthreads();

  for (int k = 2; k <= P; k <<= 1) {
    for (int j = k >> 1; j > 0; j >>= 1) {
      for (int i = tid; i < P; i += 256) {
        const int ixj = i ^ j;
        if (ixj > i) {
          const bool up = ((i & k) == 0);
          float a0 = sa[i], a1 = sa[ixj];
          if ((a0 > a1) == up) { sa[i] = a1; sa[ixj] = a0; }
          float b0 = sb[i], b1 = sb[ixj];
          if ((b0 > b1) == up) { sb[i] = b1; sb[ixj] = b0; }
        }
      }
      __syncthreads();
    }
  }

  float s = 0.0f;
  for (int r = tid; r < m; r += 256) s += fabsf(sa[r] - sb[r]);
  #pragma unroll
  for (int off = 32; off > 0; off >>= 1) s += __shfl_down(s, off);
  const int lane = tid & 63, wv = tid >> 6;
  __syncthreads();                    // all reads of sa done; safe to reuse
  if (lane == 0) sa[wv] = s;
  __syncthreads();
  if (tid == 0) {
    float tot = sa[0] + sa[1] + sa[2] + sa[3];
    atomicAdd(loss_acc, tot / (float)(m * DIM));
  }
}

__global__ __launch_bounds__(128) void k_final(
    const float* __restrict__ fill_acc, const float* __restrict__ ft,
    const float* __restrict__ loss_acc, float* __restrict__ out)
{
  __shared__ float red[K_CL];
  const int tid = threadIdx.x;
  float v = fill_acc[tid] * (1.0f / (float)N_PTS) - ft[tid];
  red[tid] = v * v;
  __syncthreads();
  for (int s = 64; s > 0; s >>= 1) {
    if (tid < s) red[tid] += red[tid + s];
    __syncthreads();
  }
  if (tid == 0) out[0] = red[0] / (float)K_CL + loss_acc[0];
}

extern "C" void kernel_launch(void* const* d_in, const int* in_sizes, int n_in,
                              void* d_out, int out_size, void* d_ws, size_t ws_size,
                              hipStream_t stream)
{
  (void)in_sizes; (void)n_in; (void)out_size; (void)ws_size;
  const float* x      = (const float*)d_in[0];
  const float* target = (const float*)d_in[1];
  const float* cc     = (const float*)d_in[2];
  const int*   pred_t = (const int*)d_in[3];
  const float* ft     = (const float*)d_in[4];
  float* out = (float*)d_out;

  char* ws = (char*)d_ws;
  float* fill_acc = (float*)(ws + 0);
  float* loss_acc = (float*)(ws + 512);
  int*   pred_x   = (int*)(ws + 1024);
  int*   idx_x    = (int*)(ws + 263168);
  int*   idx_t    = (int*)(ws + 263168 + 4194304);
  int*   count_x  = (int*)(ws + 263168 + 8388608);
  int*   count_t  = (int*)(ws + 263168 + 8388608 + 512);

  k_zero<<<1, 256, 0, stream>>>((float*)ws);
  k_pred_fill<<<N_PTS / 256, 256, 0, stream>>>(x, cc, fill_acc, pred_x);
  k_scatter<<<K_CL * 2, 1024, 0, stream>>>(pred_x, pred_t, idx_x, idx_t,
                                           count_x, count_t);
  k_w1<<<K_CL * DIM, 256, 0, stream>>>(x, target, idx_x, idx_t,
                                       count_x, count_t, loss_acc);
  k_final<<<1, 128, 0, stream>>>(fill_acc, ft, loss_acc, out);
}

// Round 2
// 974.596 us; speedup vs baseline: 1.0414x; 1.0414x over previous
//
#include <hip/hip_runtime.h>
#include <math.h>

#define N_PTS 65536
#define DIM   64
#define K_CL  128
#define EPSV  1e-8f
#define CAP   8192

// ---------------- ws layout (bytes) ----------------
// 0                : fill_acc[128] float (atomics; zeroed each launch)
// 512              : loss_acc[1]   float (zeroed each launch)
// 1024             : pred_x[N]     int
// 263168           : idx_x[128*CAP] int
// 263168+4194304   : idx_t[128*CAP] int
// 263168+8388608   : count_x[128] int
// 263168+8388608+512 : count_t[128] int

__global__ __launch_bounds__(256) void k_zero(float* ws_f) {
  ws_f[threadIdx.x] = 0.0f;  // zeros first 1024 B: fill_acc + loss_acc
}

// one thread per point; centers read via wave-uniform (scalarized) global
// loads -> s_load through scalar cache, VALU does pure v_fmac. No LDS tile.
__global__ __launch_bounds__(256) void k_pred_fill(
    const float* __restrict__ x, const float* __restrict__ centers,
    float* __restrict__ fill_acc, int* __restrict__ pred_x)
{
  __shared__ float csq[K_CL];
  __shared__ float fill_lds[K_CL];
  const int tid = threadIdx.x;

  if (tid < K_CL) {
    const float* cp = centers + tid * DIM;
    float s = 0.0f;
    #pragma unroll 8
    for (int d = 0; d < DIM; ++d) { float v = cp[d]; s += v * v; }
    csq[tid] = s;
    fill_lds[tid] = 0.0f;
  }

  const int i = blockIdx.x * 256 + tid;
  float xr[DIM];
  const float4* xp = reinterpret_cast<const float4*>(x + (size_t)i * DIM);
  #pragma unroll
  for (int q = 0; q < DIM / 4; ++q) {
    float4 v = xp[q];
    xr[4 * q + 0] = v.x; xr[4 * q + 1] = v.y;
    xr[4 * q + 2] = v.z; xr[4 * q + 3] = v.w;
  }
  float xsq = 0.0f;
  #pragma unroll
  for (int d = 0; d < DIM; ++d) xsq += xr[d] * xr[d];
  __syncthreads();

  // ---- pass 1: sumw + argmin (first-index tie-break via strict <) ----
  float sumw = 0.0f;
  float best = INFINITY;
  int   bestj = 0;
  #pragma unroll 2
  for (int j = 0; j < K_CL; ++j) {
    const float* cp = centers + j * DIM;   // uniform address -> s_load
    float d0 = 0.f, d1 = 0.f, d2a = 0.f, d3 = 0.f;
    #pragma unroll
    for (int d = 0; d < DIM; d += 4) {
      d0  += xr[d + 0] * cp[d + 0];
      d1  += xr[d + 1] * cp[d + 1];
      d2a += xr[d + 2] * cp[d + 2];
      d3  += xr[d + 3] * cp[d + 3];
    }
    float dot  = (d0 + d1) + (d2a + d3);
    float dsq  = xsq + csq[j] - 2.0f * dot;
    float dist = sqrtf(fmaxf(dsq, 0.0f));
    float w    = 1.0f / (dist + EPSV);
    sumw += w;
    if (dist < best) { best = dist; bestj = j; }
  }
  pred_x[i] = bestj;
  const float inv = 1.0f / sumw;
  const int lane = tid & 63;

  // ---- pass 2: normalized weights -> per-cluster sums ----
  #pragma unroll 2
  for (int j = 0; j < K_CL; ++j) {
    const float* cp = centers + j * DIM;   // uniform address -> s_load
    float d0 = 0.f, d1 = 0.f, d2a = 0.f, d3 = 0.f;
    #pragma unroll
    for (int d = 0; d < DIM; d += 4) {
      d0  += xr[d + 0] * cp[d + 0];
      d1  += xr[d + 1] * cp[d + 1];
      d2a += xr[d + 2] * cp[d + 2];
      d3  += xr[d + 3] * cp[d + 3];
    }
    float dot  = (d0 + d1) + (d2a + d3);
    float dsq  = xsq + csq[j] - 2.0f * dot;
    float dist = sqrtf(fmaxf(dsq, 0.0f));
    float wn   = (1.0f / (dist + EPSV)) * inv;
    #pragma unroll
    for (int off = 32; off > 0; off >>= 1) wn += __shfl_down(wn, off);
    if (lane == 0) atomicAdd(&fill_lds[j], wn);
  }
  __syncthreads();
  if (tid < K_CL) atomicAdd(&fill_acc[tid], fill_lds[tid]);
}

// stable (index-ordered) member-list build: one block per (cluster, side)
__global__ __launch_bounds__(1024) void k_scatter(
    const int* __restrict__ pred_x, const int* __restrict__ pred_t,
    int* __restrict__ idx_x, int* __restrict__ idx_t,
    int* __restrict__ count_x, int* __restrict__ count_t)
{
  const int c    = blockIdx.x >> 1;
  const int side = blockIdx.x & 1;
  const int* __restrict__ pred = side ? pred_t : pred_x;
  int* __restrict__ out = side ? idx_t : idx_x;
  int* __restrict__ cnt = side ? count_t : count_x;

  __shared__ int wsum[16];
  const int tid = threadIdx.x, lane = tid & 63, w = tid >> 6;
  int base = 0;
  for (int start = 0; start < N_PTS; start += 1024) {
    const int i = start + tid;                 // N % 1024 == 0
    const bool m = (pred[i] == c);
    unsigned long long bal = __ballot(m);
    int lp = __popcll(bal & ((1ull << lane) - 1ull));
    if (lane == 0) wsum[w] = __popcll(bal);
    __syncthreads();
    int wbase = 0, tot = 0;
    #pragma unroll
    for (int k = 0; k < 16; ++k) { int v = wsum[k]; tot += v; if (k < w) wbase += v; }
    if (m) { int pos = base + wbase + lp; if (pos < CAP) out[c * CAP + pos] = i; }
    base += tot;
    __syncthreads();
  }
  if (tid == 0) cnt[c] = base;
}

// one block per (cluster, feature): gather, bitonic sort both columns, sum
// |diff|. Size-class templated: each instantiation handles P in (PMIN, PMAX]
// so the common (small-m) case runs with tiny LDS -> high occupancy.
template<int PMAX, int PMIN>
__global__ __launch_bounds__(256) void k_w1_t(
    const float* __restrict__ x, const float* __restrict__ t,
    const int* __restrict__ idx_x, const int* __restrict__ idx_t,
    const int* __restrict__ count_x, const int* __restrict__ count_t,
    float* __restrict__ loss_acc)
{
  __shared__ float sa[PMAX];
  __shared__ float sb[PMAX];
  const int c = blockIdx.x >> 6;
  const int d = blockIdx.x & 63;
  const int cx = min(count_x[c], CAP);
  const int ct = min(count_t[c], CAP);
  const int m  = min(cx, ct);
  if (m == 0) return;

  int P = 1;
  while (P < m) P <<= 1;
  if (P > PMAX || P <= PMIN) return;   // not this size class
  const int tid = threadIdx.x;

  for (int r = tid; r < P; r += 256) {
    sa[r] = (r < m) ? x[(size_t)idx_x[c * CAP + r] * DIM + d] : INFINITY;
    sb[r] = (r < m) ? t[(size_t)idx_t[c * CAP + r] * DIM + d] : INFINITY;
  }
  __syncthreads();

  for (int k = 2; k <= P; k <<= 1) {
    for (int j = k >> 1; j > 0; j >>= 1) {
      for (int i = tid; i < P; i += 256) {
        const int ixj = i ^ j;
        if (ixj > i) {
          const bool up = ((i & k) == 0);
          float a0 = sa[i], a1 = sa[ixj];
          if ((a0 > a1) == up) { sa[i] = a1; sa[ixj] = a0; }
          float b0 = sb[i], b1 = sb[ixj];
          if ((b0 > b1) == up) { sb[i] = b1; sb[ixj] = b0; }
        }
      }
      __syncthreads();
    }
  }

  float s = 0.0f;
  for (int r = tid; r < m; r += 256) s += fabsf(sa[r] - sb[r]);
  #pragma unroll
  for (int off = 32; off > 0; off >>= 1) s += __shfl_down(s, off);
  const int lane = tid & 63, wv = tid >> 6;
  __syncthreads();                    // all reads of sa done; safe to reuse
  if (lane == 0) sa[wv] = s;
  __syncthreads();
  if (tid == 0) {
    float tot = sa[0] + sa[1] + sa[2] + sa[3];
    atomicAdd(loss_acc, tot / (float)(m * DIM));
  }
}

__global__ __launch_bounds__(128) void k_final(
    const float* __restrict__ fill_acc, const float* __restrict__ ft,
    const float* __restrict__ loss_acc, float* __restrict__ out)
{
  __shared__ float red[K_CL];
  const int tid = threadIdx.x;
  float v = fill_acc[tid] * (1.0f / (float)N_PTS) - ft[tid];
  red[tid] = v * v;
  __syncthreads();
  for (int s = 64; s > 0; s >>= 1) {
    if (tid < s) red[tid] += red[tid + s];
    __syncthreads();
  }
  if (tid == 0) out[0] = red[0] / (float)K_CL + loss_acc[0];
}

extern "C" void kernel_launch(void* const* d_in, const int* in_sizes, int n_in,
                              void* d_out, int out_size, void* d_ws, size_t ws_size,
                              hipStream_t stream)
{
  (void)in_sizes; (void)n_in; (void)out_size; (void)ws_size;
  const float* x      = (const float*)d_in[0];
  const float* target = (const float*)d_in[1];
  const float* cc     = (const float*)d_in[2];
  const int*   pred_t = (const int*)d_in[3];
  const float* ft     = (const float*)d_in[4];
  float* out = (float*)d_out;

  char* ws = (char*)d_ws;
  float* fill_acc = (float*)(ws + 0);
  float* loss_acc = (float*)(ws + 512);
  int*   pred_x   = (int*)(ws + 1024);
  int*   idx_x    = (int*)(ws + 263168);
  int*   idx_t    = (int*)(ws + 263168 + 4194304);
  int*   count_x  = (int*)(ws + 263168 + 8388608);
  int*   count_t  = (int*)(ws + 263168 + 8388608 + 512);

  k_zero<<<1, 256, 0, stream>>>((float*)ws);
  k_pred_fill<<<N_PTS / 256, 256, 0, stream>>>(x, cc, fill_acc, pred_x);
  k_scatter<<<K_CL * 2, 1024, 0, stream>>>(pred_x, pred_t, idx_x, idx_t,
                                           count_x, count_t);
  // size-class split: small (P<=512, 4 KB LDS), mid (P<=2048, 16 KB),
  // large (P<=8192, 64 KB). Each block self-selects by its cluster's m.
  k_w1_t<512, 0><<<K_CL * DIM, 256, 0, stream>>>(x, target, idx_x, idx_t,
                                                 count_x, count_t, loss_acc);
  k_w1_t<2048, 512><<<K_CL * DIM, 256, 0, stream>>>(x, target, idx_x, idx_t,
                                                    count_x, count_t, loss_acc);
  k_w1_t<8192, 2048><<<K_CL * DIM, 256, 0, stream>>>(x, target, idx_x, idx_t,
                                                     count_x, count_t, loss_acc);
  k_final<<<1, 128, 0, stream>>>(fill_acc, ft, loss_acc, out);
}

// Round 3
// 656.603 us; speedup vs baseline: 1.5457x; 1.4843x over previous
//
#include <hip/hip_runtime.h>
#include <math.h>

#define N_PTS 65536
#define DIM   64
#define K_CL  128
#define EPSV  1e-8f
#define CAP   8192

// ---------------- ws layout (bytes) ----------------
// 0                : fill_acc[128] float (atomics; zeroed each launch)
// 512              : loss_acc[1]   float (zeroed each launch)
// 1024             : pred_x[N]     int
// 263168           : idx_x[128*CAP] int
// 263168+4194304   : idx_t[128*CAP] int
// 263168+8388608   : count_x[128] int
// 263168+8388608+512 : count_t[128] int

__global__ __launch_bounds__(256) void k_zero(float* ws_f) {
  ws_f[threadIdx.x] = 0.0f;  // zeros first 1024 B: fill_acc + loss_acc
}

// one thread per point; centers read via wave-uniform (scalarized) global
// loads -> s_load through scalar cache, VALU does pure v_fmac.
__global__ __launch_bounds__(256) void k_pred_fill(
    const float* __restrict__ x, const float* __restrict__ centers,
    float* __restrict__ fill_acc, int* __restrict__ pred_x)
{
  __shared__ float csq[K_CL];
  __shared__ float fill_lds[K_CL];
  const int tid = threadIdx.x;

  if (tid < K_CL) {
    const float* cp = centers + tid * DIM;
    float s = 0.0f;
    #pragma unroll 8
    for (int d = 0; d < DIM; ++d) { float v = cp[d]; s += v * v; }
    csq[tid] = s;
    fill_lds[tid] = 0.0f;
  }

  const int i = blockIdx.x * 256 + tid;
  float xr[DIM];
  const float4* xp = reinterpret_cast<const float4*>(x + (size_t)i * DIM);
  #pragma unroll
  for (int q = 0; q < DIM / 4; ++q) {
    float4 v = xp[q];
    xr[4 * q + 0] = v.x; xr[4 * q + 1] = v.y;
    xr[4 * q + 2] = v.z; xr[4 * q + 3] = v.w;
  }
  float xsq = 0.0f;
  #pragma unroll
  for (int d = 0; d < DIM; ++d) xsq += xr[d] * xr[d];
  __syncthreads();

  // ---- pass 1: sumw + argmin (first-index tie-break via strict <) ----
  float sumw = 0.0f;
  float best = INFINITY;
  int   bestj = 0;
  #pragma unroll 2
  for (int j = 0; j < K_CL; ++j) {
    const float* cp = centers + j * DIM;   // uniform address -> s_load
    float d0 = 0.f, d1 = 0.f, d2a = 0.f, d3 = 0.f;
    #pragma unroll
    for (int d = 0; d < DIM; d += 4) {
      d0  += xr[d + 0] * cp[d + 0];
      d1  += xr[d + 1] * cp[d + 1];
      d2a += xr[d + 2] * cp[d + 2];
      d3  += xr[d + 3] * cp[d + 3];
    }
    float dot  = (d0 + d1) + (d2a + d3);
    float dsq  = xsq + csq[j] - 2.0f * dot;
    float dist = sqrtf(fmaxf(dsq, 0.0f));
    float w    = 1.0f / (dist + EPSV);
    sumw += w;
    if (dist < best) { best = dist; bestj = j; }
  }
  pred_x[i] = bestj;
  const float inv = 1.0f / sumw;
  const int lane = tid & 63;

  // ---- pass 2: normalized weights -> per-cluster sums ----
  #pragma unroll 2
  for (int j = 0; j < K_CL; ++j) {
    const float* cp = centers + j * DIM;   // uniform address -> s_load
    float d0 = 0.f, d1 = 0.f, d2a = 0.f, d3 = 0.f;
    #pragma unroll
    for (int d = 0; d < DIM; d += 4) {
      d0  += xr[d + 0] * cp[d + 0];
      d1  += xr[d + 1] * cp[d + 1];
      d2a += xr[d + 2] * cp[d + 2];
      d3  += xr[d + 3] * cp[d + 3];
    }
    float dot  = (d0 + d1) + (d2a + d3);
    float dsq  = xsq + csq[j] - 2.0f * dot;
    float dist = sqrtf(fmaxf(dsq, 0.0f));
    float wn   = (1.0f / (dist + EPSV)) * inv;
    #pragma unroll
    for (int off = 32; off > 0; off >>= 1) wn += __shfl_down(wn, off);
    if (lane == 0) atomicAdd(&fill_lds[j], wn);
  }
  __syncthreads();
  if (tid < K_CL) atomicAdd(&fill_acc[tid], fill_lds[tid]);
}

// stable (index-ordered) member-list build: one block per (cluster, side)
__global__ __launch_bounds__(1024) void k_scatter(
    const int* __restrict__ pred_x, const int* __restrict__ pred_t,
    int* __restrict__ idx_x, int* __restrict__ idx_t,
    int* __restrict__ count_x, int* __restrict__ count_t)
{
  const int c    = blockIdx.x >> 1;
  const int side = blockIdx.x & 1;
  const int* __restrict__ pred = side ? pred_t : pred_x;
  int* __restrict__ out = side ? idx_t : idx_x;
  int* __restrict__ cnt = side ? count_t : count_x;

  __shared__ int wsum[16];
  const int tid = threadIdx.x, lane = tid & 63, w = tid >> 6;
  int base = 0;
  for (int start = 0; start < N_PTS; start += 1024) {
    const int i = start + tid;                 // N % 1024 == 0
    const bool m = (pred[i] == c);
    unsigned long long bal = __ballot(m);
    int lp = __popcll(bal & ((1ull << lane) - 1ull));
    if (lane == 0) wsum[w] = __popcll(bal);
    __syncthreads();
    int wbase = 0, tot = 0;
    #pragma unroll
    for (int k = 0; k < 16; ++k) { int v = wsum[k]; tot += v; if (k < w) wbase += v; }
    if (m) { int pos = base + wbase + lp; if (pos < CAP) out[c * CAP + pos] = i; }
    base += tot;
    __syncthreads();
  }
  if (tid == 0) cnt[c] = base;
}

// ---- in-register bitonic helpers (V = 8 contiguous elements / thread) ----
__device__ __forceinline__ void ce(float& a, float& b, bool up) {
  float lo = fminf(a, b), hi = fmaxf(a, b);
  a = up ? lo : hi;
  b = up ? hi : lo;
}

// bitonic merge of 8 (phases j=4,2,1), uniform direction
__device__ __forceinline__ void merge8(float v[8], bool up) {
  ce(v[0],v[4],up); ce(v[1],v[5],up); ce(v[2],v[6],up); ce(v[3],v[7],up);
  ce(v[0],v[2],up); ce(v[1],v[3],up); ce(v[4],v[6],up); ce(v[5],v[7],up);
  ce(v[0],v[1],up); ce(v[2],v[3],up); ce(v[4],v[5],up); ce(v[6],v[7],up);
}

// full bitonic sort of 8 (stages k=2,4,8); final direction up8
__device__ __forceinline__ void sort8(float v[8], bool up8) {
  // k=2: up = ((e&2)==0)
  ce(v[0],v[1],true );  ce(v[2],v[3],false); ce(v[4],v[5],true );  ce(v[6],v[7],false);
  // k=4: up = ((e&4)==0)
  ce(v[0],v[2],true );  ce(v[1],v[3],true );  ce(v[4],v[6],false); ce(v[5],v[7],false);
  ce(v[0],v[1],true );  ce(v[2],v[3],true );  ce(v[4],v[5],false); ce(v[6],v[7],false);
  // k=8 merge with block direction
  merge8(v, up8);
}

__device__ __forceinline__ float4 sel4(float4 a, float4 b, bool takeA) {
  return takeA ? a : b;
}

// one block per (cluster, feature). Hybrid bitonic: 8 elems/thread in
// registers (initial sort + j<=4 tails), LDS float4 phases for j>=8.
// Size-class templated (PMIN, PMAX] so small clusters run with tiny LDS.
template<int PMAX, int PMIN, int BDIM>
__global__ __launch_bounds__(BDIM) void k_w1_v(
    const float* __restrict__ x, const float* __restrict__ t,
    const int* __restrict__ idx_x, const int* __restrict__ idx_t,
    const int* __restrict__ count_x, const int* __restrict__ count_t,
    float* __restrict__ loss_acc)
{
  __shared__ float sa[PMAX];
  __shared__ float sb[PMAX];
  __shared__ float red[BDIM / 64];
  const int c = blockIdx.x >> 6;
  const int d = blockIdx.x & 63;
  const int m = min(min(count_x[c], CAP), min(count_t[c], CAP));
  if (m == 0) return;
  int P = 8;
  while (P < m) P <<= 1;
  if (P > PMAX || P <= PMIN) return;   // not this size class

  const int tid  = threadIdx.x;
  const int base = tid << 3;           // chunk of 8 per thread
  const bool own = (base < P);
  float va[8], vb[8];

  if (own) {
    const int gb = c * CAP + base;
    #pragma unroll
    for (int e = 0; e < 8; ++e) {
      if (base + e < m) {
        va[e] = x[(size_t)idx_x[gb + e] * DIM + d];
        vb[e] = t[(size_t)idx_t[gb + e] * DIM + d];
      } else { va[e] = INFINITY; vb[e] = INFINITY; }
    }
    const bool u8 = ((base & 8) == 0);
    sort8(va, u8);
    sort8(vb, u8);
    if (P > 8) {
      *(float4*)&sa[base]     = make_float4(va[0],va[1],va[2],va[3]);
      *(float4*)&sa[base + 4] = make_float4(va[4],va[5],va[6],va[7]);
      *(float4*)&sb[base]     = make_float4(vb[0],vb[1],vb[2],vb[3]);
      *(float4*)&sb[base + 4] = make_float4(vb[4],vb[5],vb[6],vb[7]);
    }
  }
  if (P > 8) __syncthreads();

  for (int k = 16; k <= P; k <<= 1) {
    // ---- LDS phases: j = k/2 .. 8, four consecutive pairs per float4 ----
    for (int j = k >> 1; j >= 8; j >>= 1) {
      for (int p4 = tid * 4; p4 < (P >> 1); p4 += BDIM * 4) {
        const int i  = ((p4 & ~(j - 1)) << 1) | (p4 & (j - 1)); // 4-aligned
        const int ij = i | j;
        const bool up = ((i & k) == 0);   // uniform across the 4 pairs (k>=16)
        float4 A = *(const float4*)&sa[i];
        float4 B = *(const float4*)&sa[ij];
        float4 lo, hi;
        lo.x = fminf(A.x,B.x); hi.x = fmaxf(A.x,B.x);
        lo.y = fminf(A.y,B.y); hi.y = fmaxf(A.y,B.y);
        lo.z = fminf(A.z,B.z); hi.z = fmaxf(A.z,B.z);
        lo.w = fminf(A.w,B.w); hi.w = fmaxf(A.w,B.w);
        *(float4*)&sa[i]  = sel4(lo, hi, up);
        *(float4*)&sa[ij] = sel4(hi, lo, up);
        float4 C = *(const float4*)&sb[i];
        float4 D = *(const float4*)&sb[ij];
        lo.x = fminf(C.x,D.x); hi.x = fmaxf(C.x,D.x);
        lo.y = fminf(C.y,D.y); hi.y = fmaxf(C.y,D.y);
        lo.z = fminf(C.z,D.z); hi.z = fmaxf(C.z,D.z);
        lo.w = fminf(C.w,D.w); hi.w = fmaxf(C.w,D.w);
        *(float4*)&sb[i]  = sel4(lo, hi, up);
        *(float4*)&sb[ij] = sel4(hi, lo, up);
      }
      __syncthreads();
    }
    // ---- register tail: j = 4,2,1 within own chunk (direction uniform) ----
    const bool last = (k == P);
    if (own) {
      float4 A0 = *(const float4*)&sa[base];
      float4 A1 = *(const float4*)&sa[base + 4];
      va[0]=A0.x; va[1]=A0.y; va[2]=A0.z; va[3]=A0.w;
      va[4]=A1.x; va[5]=A1.y; va[6]=A1.z; va[7]=A1.w;
      float4 B0 = *(const float4*)&sb[base];
      float4 B1 = *(const float4*)&sb[base + 4];
      vb[0]=B0.x; vb[1]=B0.y; vb[2]=B0.z; vb[3]=B0.w;
      vb[4]=B1.x; vb[5]=B1.y; vb[6]=B1.z; vb[7]=B1.w;
      const bool up = ((base & k) == 0);
      merge8(va, up);
      merge8(vb, up);
      if (!last) {
        *(float4*)&sa[base]     = make_float4(va[0],va[1],va[2],va[3]);
        *(float4*)&sa[base + 4] = make_float4(va[4],va[5],va[6],va[7]);
        *(float4*)&sb[base]     = make_float4(vb[0],vb[1],vb[2],vb[3]);
        *(float4*)&sb[base + 4] = make_float4(vb[4],vb[5],vb[6],vb[7]);
      }
    }
    if (!last) __syncthreads();
  }

  // final sorted chunk lives in registers: accumulate |diff| directly
  float s = 0.0f;
  if (own) {
    #pragma unroll
    for (int e = 0; e < 8; ++e)
      if (base + e < m) s += fabsf(va[e] - vb[e]);
  }
  #pragma unroll
  for (int off = 32; off > 0; off >>= 1) s += __shfl_down(s, off);
  if ((tid & 63) == 0) red[tid >> 6] = s;
  __syncthreads();
  if (tid == 0) {
    float tot = 0.0f;
    #pragma unroll
    for (int w = 0; w < BDIM / 64; ++w) tot += red[w];
    atomicAdd(loss_acc, tot / (float)(m * DIM));
  }
}

__global__ __launch_bounds__(128) void k_final(
    const float* __restrict__ fill_acc, const float* __restrict__ ft,
    const float* __restrict__ loss_acc, float* __restrict__ out)
{
  __shared__ float red[K_CL];
  const int tid = threadIdx.x;
  float v = fill_acc[tid] * (1.0f / (float)N_PTS) - ft[tid];
  red[tid] = v * v;
  __syncthreads();
  for (int s = 64; s > 0; s >>= 1) {
    if (tid < s) red[tid] += red[tid + s];
    __syncthreads();
  }
  if (tid == 0) out[0] = red[0] / (float)K_CL + loss_acc[0];
}

extern "C" void kernel_launch(void* const* d_in, const int* in_sizes, int n_in,
                              void* d_out, int out_size, void* d_ws, size_t ws_size,
                              hipStream_t stream)
{
  (void)in_sizes; (void)n_in; (void)out_size; (void)ws_size;
  const float* x      = (const float*)d_in[0];
  const float* target = (const float*)d_in[1];
  const float* cc     = (const float*)d_in[2];
  const int*   pred_t = (const int*)d_in[3];
  const float* ft     = (const float*)d_in[4];
  float* out = (float*)d_out;

  char* ws = (char*)d_ws;
  float* fill_acc = (float*)(ws + 0);
  float* loss_acc = (float*)(ws + 512);
  int*   pred_x   = (int*)(ws + 1024);
  int*   idx_x    = (int*)(ws + 263168);
  int*   idx_t    = (int*)(ws + 263168 + 4194304);
  int*   count_x  = (int*)(ws + 263168 + 8388608);
  int*   count_t  = (int*)(ws + 263168 + 8388608 + 512);

  k_zero<<<1, 256, 0, stream>>>((float*)ws);
  k_pred_fill<<<N_PTS / 256, 256, 0, stream>>>(x, cc, fill_acc, pred_x);
  k_scatter<<<K_CL * 2, 1024, 0, stream>>>(pred_x, pred_t, idx_x, idx_t,
                                           count_x, count_t);
  // size classes: small (P<=512, 4 KB LDS, 256 thr), mid (P<=2048, 16 KB,
  // 256 thr), large (P<=8192, 64 KB, 1024 thr -> 32 waves/CU).
  k_w1_v<512, 0, 256><<<K_CL * DIM, 256, 0, stream>>>(
      x, target, idx_x, idx_t, count_x, count_t, loss_acc);
  k_w1_v<2048, 512, 256><<<K_CL * DIM, 256, 0, stream>>>(
      x, target, idx_x, idx_t, count_x, count_t, loss_acc);
  k_w1_v<8192, 2048, 1024><<<K_CL * DIM, 1024, 0, stream>>>(
      x, target, idx_x, idx_t, count_x, count_t, loss_acc);
  k_final<<<1, 128, 0, stream>>>(fill_acc, ft, loss_acc, out);
}

// Round 4
// 653.365 us; speedup vs baseline: 1.5534x; 1.0050x over previous
//
#include <hip/hip_runtime.h>
#include <math.h>

#define N_PTS 65536
#define DIM   64
#define K_CL  128
#define EPSV  1e-8f
#define CAP   8192

// ---------------- ws layout (bytes) ----------------
// 0                : fill_acc[128] float (atomics; zeroed each launch)
// 512              : loss_acc[1]   float (zeroed each launch)
// 1024             : pred_x[N]     int
// 263168           : idx_x[128*CAP] int
// 263168+4194304   : idx_t[128*CAP] int
// 263168+8388608   : count_x[128] int
// 263168+8388608+512 : count_t[128] int

__global__ __launch_bounds__(256) void k_zero(float* ws_f) {
  ws_f[threadIdx.x] = 0.0f;  // zeros first 1024 B: fill_acc + loss_acc
}

// one thread per point; centers read via wave-uniform (scalarized) global
// loads -> s_load through scalar cache, VALU does pure v_fmac.
__global__ __launch_bounds__(256) void k_pred_fill(
    const float* __restrict__ x, const float* __restrict__ centers,
    float* __restrict__ fill_acc, int* __restrict__ pred_x)
{
  __shared__ float csq[K_CL];
  __shared__ float fill_lds[K_CL];
  const int tid = threadIdx.x;

  if (tid < K_CL) {
    const float* cp = centers + tid * DIM;
    float s = 0.0f;
    #pragma unroll 8
    for (int d = 0; d < DIM; ++d) { float v = cp[d]; s += v * v; }
    csq[tid] = s;
    fill_lds[tid] = 0.0f;
  }

  const int i = blockIdx.x * 256 + tid;
  float xr[DIM];
  const float4* xp = reinterpret_cast<const float4*>(x + (size_t)i * DIM);
  #pragma unroll
  for (int q = 0; q < DIM / 4; ++q) {
    float4 v = xp[q];
    xr[4 * q + 0] = v.x; xr[4 * q + 1] = v.y;
    xr[4 * q + 2] = v.z; xr[4 * q + 3] = v.w;
  }
  float xsq = 0.0f;
  #pragma unroll
  for (int d = 0; d < DIM; ++d) xsq += xr[d] * xr[d];
  __syncthreads();

  // ---- pass 1: sumw + argmin (first-index tie-break via strict <) ----
  float sumw = 0.0f;
  float best = INFINITY;
  int   bestj = 0;
  #pragma unroll 2
  for (int j = 0; j < K_CL; ++j) {
    const float* cp = centers + j * DIM;   // uniform address -> s_load
    float d0 = 0.f, d1 = 0.f, d2a = 0.f, d3 = 0.f;
    #pragma unroll
    for (int d = 0; d < DIM; d += 4) {
      d0  += xr[d + 0] * cp[d + 0];
      d1  += xr[d + 1] * cp[d + 1];
      d2a += xr[d + 2] * cp[d + 2];
      d3  += xr[d + 3] * cp[d + 3];
    }
    float dot  = (d0 + d1) + (d2a + d3);
    float dsq  = xsq + csq[j] - 2.0f * dot;
    float dist = sqrtf(fmaxf(dsq, 0.0f));
    float w    = 1.0f / (dist + EPSV);
    sumw += w;
    if (dist < best) { best = dist; bestj = j; }
  }
  pred_x[i] = bestj;
  const float inv = 1.0f / sumw;
  const int lane = tid & 63;

  // ---- pass 2: normalized weights -> per-cluster sums ----
  #pragma unroll 2
  for (int j = 0; j < K_CL; ++j) {
    const float* cp = centers + j * DIM;   // uniform address -> s_load
    float d0 = 0.f, d1 = 0.f, d2a = 0.f, d3 = 0.f;
    #pragma unroll
    for (int d = 0; d < DIM; d += 4) {
      d0  += xr[d + 0] * cp[d + 0];
      d1  += xr[d + 1] * cp[d + 1];
      d2a += xr[d + 2] * cp[d + 2];
      d3  += xr[d + 3] * cp[d + 3];
    }
    float dot  = (d0 + d1) + (d2a + d3);
    float dsq  = xsq + csq[j] - 2.0f * dot;
    float dist = sqrtf(fmaxf(dsq, 0.0f));
    float wn   = (1.0f / (dist + EPSV)) * inv;
    #pragma unroll
    for (int off = 32; off > 0; off >>= 1) wn += __shfl_down(wn, off);
    if (lane == 0) atomicAdd(&fill_lds[j], wn);
  }
  __syncthreads();
  if (tid < K_CL) atomicAdd(&fill_acc[tid], fill_lds[tid]);
}

// stable (index-ordered) member-list build: one block per (cluster, side)
__global__ __launch_bounds__(1024) void k_scatter(
    const int* __restrict__ pred_x, const int* __restrict__ pred_t,
    int* __restrict__ idx_x, int* __restrict__ idx_t,
    int* __restrict__ count_x, int* __restrict__ count_t)
{
  const int c    = blockIdx.x >> 1;
  const int side = blockIdx.x & 1;
  const int* __restrict__ pred = side ? pred_t : pred_x;
  int* __restrict__ out = side ? idx_t : idx_x;
  int* __restrict__ cnt = side ? count_t : count_x;

  __shared__ int wsum[16];
  const int tid = threadIdx.x, lane = tid & 63, w = tid >> 6;
  int base = 0;
  for (int start = 0; start < N_PTS; start += 1024) {
    const int i = start + tid;                 // N % 1024 == 0
    const bool m = (pred[i] == c);
    unsigned long long bal = __ballot(m);
    int lp = __popcll(bal & ((1ull << lane) - 1ull));
    if (lane == 0) wsum[w] = __popcll(bal);
    __syncthreads();
    int wbase = 0, tot = 0;
    #pragma unroll
    for (int k = 0; k < 16; ++k) { int v = wsum[k]; tot += v; if (k < w) wbase += v; }
    if (m) { int pos = base + wbase + lp; if (pos < CAP) out[c * CAP + pos] = i; }
    base += tot;
    __syncthreads();
  }
  if (tid == 0) cnt[c] = base;
}

// XOR bank swizzle at float4 granularity: XOR bank-quad bits [4:2] with row
// bits [7:5]. Preserves 16B alignment/contiguity of every access here; kills
// the 16-way quad-bank aliasing of the j=8/16 phases.
__device__ __forceinline__ int sw(int i) {
  return i ^ (((i >> 5) & 7) << 2);
}

// ---- in-register bitonic helpers (V = 8 contiguous elements / thread) ----
__device__ __forceinline__ void ce(float& a, float& b, bool up) {
  float lo = fminf(a, b), hi = fmaxf(a, b);
  a = up ? lo : hi;
  b = up ? hi : lo;
}

// bitonic merge of 8 (phases j=4,2,1), uniform direction
__device__ __forceinline__ void merge8(float v[8], bool up) {
  ce(v[0],v[4],up); ce(v[1],v[5],up); ce(v[2],v[6],up); ce(v[3],v[7],up);
  ce(v[0],v[2],up); ce(v[1],v[3],up); ce(v[4],v[6],up); ce(v[5],v[7],up);
  ce(v[0],v[1],up); ce(v[2],v[3],up); ce(v[4],v[5],up); ce(v[6],v[7],up);
}

// full bitonic sort of 8 (stages k=2,4,8); final direction up8
__device__ __forceinline__ void sort8(float v[8], bool up8) {
  ce(v[0],v[1],true );  ce(v[2],v[3],false); ce(v[4],v[5],true );  ce(v[6],v[7],false);
  ce(v[0],v[2],true );  ce(v[1],v[3],true );  ce(v[4],v[6],false); ce(v[5],v[7],false);
  ce(v[0],v[1],true );  ce(v[2],v[3],true );  ce(v[4],v[5],false); ce(v[6],v[7],false);
  merge8(v, up8);
}

__device__ __forceinline__ float4 sel4(float4 a, float4 b, bool takeA) {
  return takeA ? a : b;
}

// one block per (cluster, feature). Hybrid bitonic: 8 elems/thread in
// registers (initial sort + j<=4 tails), LDS float4 phases for j>=8,
// bank-swizzled. Size-class templated (PMIN, PMAX].
template<int PMAX, int PMIN, int BDIM>
__global__ __launch_bounds__(BDIM) void k_w1_v(
    const float* __restrict__ x, const float* __restrict__ t,
    const int* __restrict__ idx_x, const int* __restrict__ idx_t,
    const int* __restrict__ count_x, const int* __restrict__ count_t,
    float* __restrict__ loss_acc)
{
  __shared__ float sa[PMAX];
  __shared__ float sb[PMAX];
  __shared__ float red[BDIM / 64];
  const int c = blockIdx.x >> 6;
  const int d = blockIdx.x & 63;
  const int m = min(min(count_x[c], CAP), min(count_t[c], CAP));
  if (m == 0) return;
  int P = 8;
  while (P < m) P <<= 1;
  if (P > PMAX || P <= PMIN) return;   // not this size class

  const int tid  = threadIdx.x;
  const int base = tid << 3;           // chunk of 8 per thread
  const bool own = (base < P);
  float va[8], vb[8];

  if (own) {
    const int gb = c * CAP + base;
    #pragma unroll
    for (int e = 0; e < 8; ++e) {
      if (base + e < m) {
        va[e] = x[(size_t)idx_x[gb + e] * DIM + d];
        vb[e] = t[(size_t)idx_t[gb + e] * DIM + d];
      } else { va[e] = INFINITY; vb[e] = INFINITY; }
    }
    const bool u8 = ((base & 8) == 0);
    sort8(va, u8);
    sort8(vb, u8);
    if (P > 8) {
      *(float4*)&sa[sw(base)]     = make_float4(va[0],va[1],va[2],va[3]);
      *(float4*)&sa[sw(base + 4)] = make_float4(va[4],va[5],va[6],va[7]);
      *(float4*)&sb[sw(base)]     = make_float4(vb[0],vb[1],vb[2],vb[3]);
      *(float4*)&sb[sw(base + 4)] = make_float4(vb[4],vb[5],vb[6],vb[7]);
    }
  }
  if (P > 8) __syncthreads();

  for (int k = 16; k <= P; k <<= 1) {
    // ---- LDS phases: j = k/2 .. 8, four consecutive pairs per float4 ----
    for (int j = k >> 1; j >= 8; j >>= 1) {
      for (int p4 = tid * 4; p4 < (P >> 1); p4 += BDIM * 4) {
        const int i  = ((p4 & ~(j - 1)) << 1) | (p4 & (j - 1)); // 4-aligned
        const int ij = i | j;
        const bool up = ((i & k) == 0);   // uniform across the 4 pairs (k>=16)
        const int si = sw(i), sij = sw(ij);
        float4 A = *(const float4*)&sa[si];
        float4 B = *(const float4*)&sa[sij];
        float4 lo, hi;
        lo.x = fminf(A.x,B.x); hi.x = fmaxf(A.x,B.x);
        lo.y = fminf(A.y,B.y); hi.y = fmaxf(A.y,B.y);
        lo.z = fminf(A.z,B.z); hi.z = fmaxf(A.z,B.z);
        lo.w = fminf(A.w,B.w); hi.w = fmaxf(A.w,B.w);
        *(float4*)&sa[si]  = sel4(lo, hi, up);
        *(float4*)&sa[sij] = sel4(hi, lo, up);
        float4 C = *(const float4*)&sb[si];
        float4 D = *(const float4*)&sb[sij];
        lo.x = fminf(C.x,D.x); hi.x = fmaxf(C.x,D.x);
        lo.y = fminf(C.y,D.y); hi.y = fmaxf(C.y,D.y);
        lo.z = fminf(C.z,D.z); hi.z = fmaxf(C.z,D.z);
        lo.w = fminf(C.w,D.w); hi.w = fmaxf(C.w,D.w);
        *(float4*)&sb[si]  = sel4(lo, hi, up);
        *(float4*)&sb[sij] = sel4(hi, lo, up);
      }
      __syncthreads();
    }
    // ---- register tail: j = 4,2,1 within own chunk (direction uniform) ----
    const bool last = (k == P);
    if (own) {
      float4 A0 = *(const float4*)&sa[sw(base)];
      float4 A1 = *(const float4*)&sa[sw(base + 4)];
      va[0]=A0.x; va[1]=A0.y; va[2]=A0.z; va[3]=A0.w;
      va[4]=A1.x; va[5]=A1.y; va[6]=A1.z; va[7]=A1.w;
      float4 B0 = *(const float4*)&sb[sw(base)];
      float4 B1 = *(const float4*)&sb[sw(base + 4)];
      vb[0]=B0.x; vb[1]=B0.y; vb[2]=B0.z; vb[3]=B0.w;
      vb[4]=B1.x; vb[5]=B1.y; vb[6]=B1.z; vb[7]=B1.w;
      const bool up = ((base & k) == 0);
      merge8(va, up);
      merge8(vb, up);
      if (!last) {
        *(float4*)&sa[sw(base)]     = make_float4(va[0],va[1],va[2],va[3]);
        *(float4*)&sa[sw(base + 4)] = make_float4(va[4],va[5],va[6],va[7]);
        *(float4*)&sb[sw(base)]     = make_float4(vb[0],vb[1],vb[2],vb[3]);
        *(float4*)&sb[sw(base + 4)] = make_float4(vb[4],vb[5],vb[6],vb[7]);
      }
    }
    if (!last) __syncthreads();
  }

  // final sorted chunk lives in registers: accumulate |diff| directly
  float s = 0.0f;
  if (own) {
    #pragma unroll
    for (int e = 0; e < 8; ++e)
      if (base + e < m) s += fabsf(va[e] - vb[e]);
  }
  #pragma unroll
  for (int off = 32; off > 0; off >>= 1) s += __shfl_down(s, off);
  if ((tid & 63) == 0) red[tid >> 6] = s;
  __syncthreads();
  if (tid == 0) {
    float tot = 0.0f;
    #pragma unroll
    for (int w = 0; w < BDIM / 64; ++w) tot += red[w];
    atomicAdd(loss_acc, tot / (float)(m * DIM));
  }
}

__global__ __launch_bounds__(128) void k_final(
    const float* __restrict__ fill_acc, const float* __restrict__ ft,
    const float* __restrict__ loss_acc, float* __restrict__ out)
{
  __shared__ float red[K_CL];
  const int tid = threadIdx.x;
  float v = fill_acc[tid] * (1.0f / (float)N_PTS) - ft[tid];
  red[tid] = v * v;
  __syncthreads();
  for (int s = 64; s > 0; s >>= 1) {
    if (tid < s) red[tid] += red[tid + s];
    __syncthreads();
  }
  if (tid == 0) out[0] = red[0] / (float)K_CL + loss_acc[0];
}

extern "C" void kernel_launch(void* const* d_in, const int* in_sizes, int n_in,
                              void* d_out, int out_size, void* d_ws, size_t ws_size,
                              hipStream_t stream)
{
  (void)in_sizes; (void)n_in; (void)out_size; (void)ws_size;
  const float* x      = (const float*)d_in[0];
  const float* target = (const float*)d_in[1];
  const float* cc     = (const float*)d_in[2];
  const int*   pred_t = (const int*)d_in[3];
  const float* ft     = (const float*)d_in[4];
  float* out = (float*)d_out;

  char* ws = (char*)d_ws;
  float* fill_acc = (float*)(ws + 0);
  float* loss_acc = (float*)(ws + 512);
  int*   pred_x   = (int*)(ws + 1024);
  int*   idx_x    = (int*)(ws + 263168);
  int*   idx_t    = (int*)(ws + 263168 + 4194304);
  int*   count_x  = (int*)(ws + 263168 + 8388608);
  int*   count_t  = (int*)(ws + 263168 + 8388608 + 512);

  k_zero<<<1, 256, 0, stream>>>((float*)ws);
  k_pred_fill<<<N_PTS / 256, 256, 0, stream>>>(x, cc, fill_acc, pred_x);
  k_scatter<<<K_CL * 2, 1024, 0, stream>>>(pred_x, pred_t, idx_x, idx_t,
                                           count_x, count_t);
  // size classes: small (P<=512, 4 KB LDS, 256 thr), mid (P<=2048, 16 KB,
  // 256 thr), large (P<=8192, 64 KB, 1024 thr -> 32 waves/CU).
  k_w1_v<512, 0, 256><<<K_CL * DIM, 256, 0, stream>>>(
      x, target, idx_x, idx_t, count_x, count_t, loss_acc);
  k_w1_v<2048, 512, 256><<<K_CL * DIM, 256, 0, stream>>>(
      x, target, idx_x, idx_t, count_x, count_t, loss_acc);
  k_w1_v<8192, 2048, 1024><<<K_CL * DIM, 1024, 0, stream>>>(
      x, target, idx_x, idx_t, count_x, count_t, loss_acc);
  k_final<<<1, 128, 0, stream>>>(fill_acc, ft, loss_acc, out);
}